// Round 6
// baseline (959.191 us; speedup 1.0000x reference)
//
#include <hip/hip_runtime.h>
#include <hip/hip_bf16.h>

#define BATCH 256
#define NDIM  4096
#define STEPS 16
#define EPS_RMS 1.1920929e-07f

typedef _Float16 f16x8 __attribute__((ext_vector_type(8)));
typedef float  f32x4  __attribute__((ext_vector_type(4)));
typedef unsigned short u16x4 __attribute__((ext_vector_type(4)));
typedef unsigned short u16x8 __attribute__((ext_vector_type(8)));
typedef unsigned int   u32x4 __attribute__((ext_vector_type(4)));

#define AS1 __attribute__((address_space(1)))
#define AS3 __attribute__((address_space(3)))
#define GLDS16(gp, lp) __builtin_amdgcn_global_load_lds( \
    (const AS1 void*)(gp), (AS3 void*)(lp), 16, 0, 0)
#define SBAR() do { asm volatile("" ::: "memory"); \
                    __builtin_amdgcn_s_barrier();  \
                    asm volatile("" ::: "memory"); } while (0)

__device__ __forceinline__ unsigned short f2h(float f) {
  _Float16 h = (_Float16)f;
  union { _Float16 h; unsigned short u; } v; v.h = h; return v.u;
}
__device__ __forceinline__ float h2f(unsigned short u) {
  union { unsigned short u; _Float16 h; } v; v.u = u; return (float)v.h;
}

__device__ __forceinline__ float block_reduce_sum_512(float v) {
  __shared__ float ws[8];
  __shared__ float tot;
  #pragma unroll
  for (int off = 32; off > 0; off >>= 1) v += __shfl_down(v, off, 64);
  int lane = threadIdx.x & 63, w = threadIdx.x >> 6;
  if (lane == 0) ws[w] = v;
  __syncthreads();
  if (threadIdx.x == 0) {
    float t = 0.f;
    #pragma unroll
    for (int i = 0; i < 8; ++i) t += ws[i];
    tot = t;
  }
  __syncthreads();
  return tot;
}

// ---------------- W (f32, [k][n]) -> Wt (fp16, [n][k]) ----------------
__global__ __launch_bounds__(256) void transpose_w(
    const float* __restrict__ W, unsigned short* __restrict__ Wt) {
  __shared__ float tile[64][65];
  int n0 = blockIdx.x * 64;
  int k0 = blockIdx.y * 64;
  int t = threadIdx.x;
  int r = t >> 4, c4 = (t & 15) * 4;
  #pragma unroll
  for (int p = 0; p < 4; ++p) {
    f32x4 v = *(const f32x4*)(W + (size_t)(k0 + r + 16 * p) * NDIM + n0 + c4);
    tile[r + 16 * p][c4 + 0] = v[0];
    tile[r + 16 * p][c4 + 1] = v[1];
    tile[r + 16 * p][c4 + 2] = v[2];
    tile[r + 16 * p][c4 + 3] = v[3];
  }
  __syncthreads();
  #pragma unroll
  for (int p = 0; p < 4; ++p) {
    int nr = r + 16 * p;
    u16x4 o;
    #pragma unroll
    for (int j = 0; j < 4; ++j) o[j] = f2h(tile[c4 + j][nr]);
    *(u16x4*)(Wt + (size_t)(n0 + nr) * NDIM + k0 + c4) = o;
  }
}

// ---------------- column multipliers + rowsum zeroing ----------------
__global__ void init_colmul(const float* __restrict__ iscale,
                            const float* __restrict__ oscale,
                            const int* __restrict__ ipos, const int* __restrict__ opos,
                            float* __restrict__ icm, float* __restrict__ ocm,
                            float* __restrict__ rowsum) {
  int c = blockIdx.x * 256 + threadIdx.x;
  if (c >= NDIM) return;
  rowsum[c] = 0.f;   // [16][256] = 4096 entries, zeroed every launch
  float iv = 1.f, ov = 1.f;
  #pragma unroll
  for (int i = 0; i < 16; ++i) {
    if (ipos[i] == c) iv *= iscale[i];
    if (opos[i] == c) ov *= oscale[i];
  }
  icm[c] = iv; ocm[c] = ov;
}

// ---------------- step 0: A'_0 = tanh(B + x*icm)*nw, rowsum[0] ----------------
__global__ __launch_bounds__(512) void step0_kernel(
    const float* __restrict__ x, const float* __restrict__ bias,
    const float* __restrict__ icm, const float* __restrict__ nw,
    unsigned short* __restrict__ A0, float* __restrict__ rs0) {
  int row = blockIdx.x;
  int tid = threadIdx.x;
  const float* xr = x + (size_t)row * NDIM;
  float a[8];
  float sq = 0.f;
  #pragma unroll
  for (int p = 0; p < 2; ++p) {
    int c = p * 2048 + tid * 4;
    f32x4 xv = *(const f32x4*)(xr + c);
    f32x4 bv = *(const f32x4*)(bias + c);
    f32x4 ic = *(const f32x4*)(icm + c);
    #pragma unroll
    for (int j = 0; j < 4; ++j) {
      float av = tanhf(bv[j] + xv[j] * ic[j]);
      a[p * 4 + j] = av;
      sq += av * av;
    }
  }
  float tot = block_reduce_sum_512(sq);
  if (tid == 0) rs0[row] = tot;
  unsigned short* arow = A0 + (size_t)row * NDIM;
  #pragma unroll
  for (int p = 0; p < 2; ++p) {
    int c = p * 2048 + tid * 4;
    f32x4 nv = *(const f32x4*)(nw + c);
    u16x4 hs;
    #pragma unroll
    for (int j = 0; j < 4; ++j) hs[j] = f2h(a[p * 4 + j] * nv[j]);
    *(u16x4*)(arow + c) = hs;
  }
}

// ---------------- fused step t: GEMM(full K) + bias + tanh + rowsum +
//                  A'_t store + out_{t-1} write ----------------
// grid (64 n-tiles, 4 m-tiles) = 256 blocks, 128 threads = 2 waves (64x32 tiles).
__global__ __launch_bounds__(128) void fused_step(
    const unsigned short* __restrict__ Aprev,  // A'_{t-1} fp16 [256][4096]
    unsigned short* __restrict__ Acur,         // A'_t fp16
    const unsigned short* __restrict__ Wt,     // fp16 [n][k]
    const float* __restrict__ bias, const float* __restrict__ nw,
    const float* __restrict__ ocm,
    const float* __restrict__ rs_prev, float* __restrict__ rs_cur,
    float* __restrict__ out, int tm1) {
  __shared__ __align__(16) unsigned short As[2][64 * 64];
  __shared__ __align__(16) unsigned short Bs[2][64 * 64];
  __shared__ float scale_s[64];

  const int tid = threadIdx.x;
  const int n0 = blockIdx.x * 64;
  const int m0 = blockIdx.y * 64;
  const int wave = tid >> 6, lane = tid & 63;
  const int wn = wave * 32;
  const int l15 = lane & 15;
  const int g = lane >> 4;             // 0..3
  const int q = l15 & 7;               // read-side swizzle key
  const int srow = tid >> 3;           // 0..15 staging row-in-group
  const int sch = tid & 7;             // staging chunk
  const int koff = (sch ^ (srow & 7)) * 8;  // swizzled k offset (elems)

  // per-lane global source pointers (4 row-groups each for A and B)
  const unsigned short* aP[4];
  const unsigned short* bP[4];
  #pragma unroll
  for (int i = 0; i < 4; ++i) {
    aP[i] = Aprev + (size_t)(m0 + i * 16 + srow) * NDIM + koff;
    bP[i] = Wt + (size_t)(n0 + i * 16 + srow) * NDIM + koff;
  }

  f32x4 acc[4][2];
  f32x4 zero = {0.f, 0.f, 0.f, 0.f};
  #pragma unroll
  for (int i = 0; i < 4; ++i) { acc[i][0] = zero; acc[i][1] = zero; }

  // prologue: stage k-tile 0 into buffer 0
  #pragma unroll
  for (int i = 0; i < 4; ++i) {
    GLDS16(aP[i], &As[0][(i * 16 + srow) * 64 + sch * 8]);
    GLDS16(bP[i], &Bs[0][(i * 16 + srow) * 64 + sch * 8]);
  }

  for (int it = 0; it < 64; ++it) {
    const int p = it & 1;
    SBAR();  // buf[1-p] free
    {
      const int kb = (it < 63 ? (it + 1) : 63) * 64;  // clamp: tail re-stage, unread
      #pragma unroll
      for (int i = 0; i < 4; ++i) {
        GLDS16(aP[i] + kb, &As[1 - p][(i * 16 + srow) * 64 + sch * 8]);
        GLDS16(bP[i] + kb, &Bs[1 - p][(i * 16 + srow) * 64 + sch * 8]);
      }
    }
    asm volatile("s_waitcnt vmcnt(8)" ::: "memory");  // tile it landed
    SBAR();
    #pragma unroll
    for (int kk = 0; kk < 2; ++kk) {
      f16x8 af[4], bfr[2];
      #pragma unroll
      for (int mf = 0; mf < 4; ++mf)
        af[mf] = *(const f16x8*)&As[p][(mf * 16 + l15) * 64 + (((kk << 2) + g) ^ q) * 8];
      #pragma unroll
      for (int nf = 0; nf < 2; ++nf)
        bfr[nf] = *(const f16x8*)&Bs[p][(wn + nf * 16 + l15) * 64 + (((kk << 2) + g) ^ q) * 8];
      #pragma unroll
      for (int mf = 0; mf < 4; ++mf)
        #pragma unroll
        for (int nf = 0; nf < 2; ++nf)
          acc[mf][nf] = __builtin_amdgcn_mfma_f32_16x16x32_f16(af[mf], bfr[nf], acc[mf][nf], 0, 0, 0);
    }
  }

  // ---- epilogue ----
  __syncthreads();
  if (tid < 64) scale_s[tid] = rsqrtf(rs_prev[m0 + tid] * (1.0f / NDIM) + EPS_RMS);
  __syncthreads();

  float bv[2], nwv[2];
  #pragma unroll
  for (int nf = 0; nf < 2; ++nf) {
    bv[nf] = bias[n0 + wn + nf * 16 + l15];
    nwv[nf] = nw[n0 + wn + nf * 16 + l15];
  }
  unsigned short* Ast = &As[0][0];  // reuse 8KB for A'_t tile [64][64]

  #pragma unroll
  for (int mf = 0; mf < 4; ++mf) {
    #pragma unroll
    for (int r = 0; r < 4; ++r) {
      int rl = mf * 16 + g * 4 + r;
      float rp = scale_s[rl];
      float s2 = 0.f;
      #pragma unroll
      for (int nf = 0; nf < 2; ++nf) {
        float a = tanhf(acc[mf][nf][r] * rp + bv[nf]);
        s2 += a * a;
        Ast[rl * 64 + wn + nf * 16 + l15] = f2h(a * nwv[nf]);
      }
      s2 += __shfl_xor(s2, 1, 64);
      s2 += __shfl_xor(s2, 2, 64);
      s2 += __shfl_xor(s2, 4, 64);
      s2 += __shfl_xor(s2, 8, 64);
      if (l15 == 0) atomicAdd(rs_cur + m0 + rl, s2);
    }
  }
  __syncthreads();

  // linear coalesced A'_t store
  {
    int cl = (tid & 7) * 8;
    #pragma unroll
    for (int rd = 0; rd < 4; ++rd) {
      int rl = rd * 16 + (tid >> 3);
      *(u16x8*)(Acur + (size_t)(m0 + rl) * NDIM + n0 + cl) = *(u16x8*)&Ast[rl * 64 + cl];
    }
  }

  // out_{t-1} = A'_{t-1} * r_{t-1} * ocm  (linear, L2-hot re-read)
  {
    int cl = (tid & 7) * 8;
    f32x4 oc0 = *(const f32x4*)(ocm + n0 + cl);
    f32x4 oc1 = *(const f32x4*)(ocm + n0 + cl + 4);
    #pragma unroll
    for (int rd = 0; rd < 4; ++rd) {
      int rl = rd * 16 + (tid >> 3);
      u16x8 av = *(const u16x8*)(Aprev + (size_t)(m0 + rl) * NDIM + n0 + cl);
      float rp = scale_s[rl];
      f32x4 o0, o1;
      #pragma unroll
      for (int j = 0; j < 4; ++j) {
        o0[j] = h2f(av[j]) * rp * oc0[j];
        o1[j] = h2f(av[j + 4]) * rp * oc1[j];
      }
      float* orow = out + ((size_t)(m0 + rl) * STEPS + tm1) * NDIM + n0 + cl;
      *(f32x4*)orow = o0;
      *(f32x4*)(orow + 4) = o1;
    }
  }
}

// ---------------- final: out_15 + h_final ----------------
__global__ __launch_bounds__(256) void final_kernel(
    const unsigned short* __restrict__ Alast, const float* __restrict__ rs15,
    const float* __restrict__ ocm,
    float* __restrict__ out, float* __restrict__ hfin) {
  int row = blockIdx.x;
  int tid = threadIdx.x;
  float rp = rsqrtf(rs15[row] * (1.0f / NDIM) + EPS_RMS);
  const unsigned short* ar = Alast + (size_t)row * NDIM;
  float* orow = out + ((size_t)row * STEPS + (STEPS - 1)) * NDIM;
  float* frow = hfin + (size_t)row * NDIM;
  #pragma unroll
  for (int j = 0; j < 2; ++j) {
    int c = tid * 16 + j * 8;
    u16x8 av = *(const u16x8*)(ar + c);
    f32x4 oc0 = *(const f32x4*)(ocm + c);
    f32x4 oc1 = *(const f32x4*)(ocm + c + 4);
    f32x4 h0, h1, o0, o1;
    #pragma unroll
    for (int k = 0; k < 4; ++k) {
      h0[k] = h2f(av[k]) * rp;
      h1[k] = h2f(av[k + 4]) * rp;
      o0[k] = h0[k] * oc0[k];
      o1[k] = h1[k] * oc1[k];
    }
    *(f32x4*)(orow + c) = o0;
    *(f32x4*)(orow + c + 4) = o1;
    *(f32x4*)(frow + c) = h0;
    *(f32x4*)(frow + c + 4) = h1;
  }
}

extern "C" void kernel_launch(void* const* d_in, const int* in_sizes, int n_in,
                              void* d_out, int out_size, void* d_ws, size_t ws_size,
                              hipStream_t stream) {
  (void)in_sizes; (void)n_in; (void)out_size; (void)ws_size;
  const float* x      = (const float*)d_in[0];
  const float* W      = (const float*)d_in[1];
  const float* Bb     = (const float*)d_in[2];
  const float* iscale = (const float*)d_in[3];
  const float* oscale = (const float*)d_in[4];
  const float* nw     = (const float*)d_in[5];
  const int* ipos = (const int*)d_in[6];
  const int* opos = (const int*)d_in[7];
  // d_in[8] = steps (fixed at 16 by the problem spec).

  char* ws = (char*)d_ws;
  unsigned short* Wt    = (unsigned short*)(ws);             // 32 MiB fp16
  unsigned short* abuf0 = (unsigned short*)(ws + 33554432);  // 2 MiB fp16
  unsigned short* abuf1 = (unsigned short*)(ws + 35651584);  // 2 MiB fp16
  float* icm            = (float*)(ws + 37748736);           // 16 KiB
  float* ocm            = (float*)(ws + 37765120);           // 16 KiB
  float* rowsum         = (float*)(ws + 37781504);           // 16 KiB [16][256]

  float* out  = (float*)d_out;
  float* hfin = out + (size_t)BATCH * STEPS * NDIM;

  hipLaunchKernelGGL(transpose_w, dim3(64, 64), dim3(256), 0, stream, W, Wt);
  hipLaunchKernelGGL(init_colmul, dim3(16), dim3(256), 0, stream,
                     iscale, oscale, ipos, opos, icm, ocm, rowsum);
  hipLaunchKernelGGL(step0_kernel, dim3(256), dim3(512), 0, stream,
                     x, Bb, icm, nw, abuf0, rowsum);
  for (int t = 1; t < STEPS; ++t) {
    const unsigned short* Ap = ((t - 1) & 1) ? abuf1 : abuf0;
    unsigned short* Ac = (t & 1) ? abuf1 : abuf0;
    hipLaunchKernelGGL(fused_step, dim3(64, 4), dim3(128), 0, stream,
                       Ap, Ac, Wt, Bb, nw, ocm,
                       rowsum + (t - 1) * 256, rowsum + t * 256, out, t - 1);
  }
  hipLaunchKernelGGL(final_kernel, dim3(256), dim3(256), 0, stream,
                     abuf1, rowsum + 15 * 256, ocm, out, hfin);
}

// Round 7
// 403.603 us; speedup vs baseline: 2.3766x; 2.3766x over previous
//
#include <hip/hip_runtime.h>
#include <hip/hip_bf16.h>

#define BATCH 256
#define NDIM  4096
#define STEPS 16
#define EPS_RMS 1.1920929e-07f

typedef _Float16 f16x8 __attribute__((ext_vector_type(8)));
typedef float  f32x4  __attribute__((ext_vector_type(4)));
typedef unsigned short u16x4 __attribute__((ext_vector_type(4)));
typedef unsigned int   u32x4 __attribute__((ext_vector_type(4)));

#define AS1 __attribute__((address_space(1)))
#define AS3 __attribute__((address_space(3)))
#define GLDS16(gp, lp) __builtin_amdgcn_global_load_lds( \
    (const AS1 void*)(gp), (AS3 void*)(lp), 16, 0, 0)
#define SBAR() do { asm volatile("" ::: "memory"); \
                    __builtin_amdgcn_s_barrier();  \
                    asm volatile("" ::: "memory"); } while (0)

__device__ __forceinline__ unsigned short f2h(float f) {
  _Float16 h = (_Float16)f;
  union { _Float16 h; unsigned short u; } v; v.h = h; return v.u;
}

__device__ __forceinline__ float block_reduce_sum_512(float v) {
  __shared__ float ws[8];
  __shared__ float tot;
  #pragma unroll
  for (int off = 32; off > 0; off >>= 1) v += __shfl_down(v, off, 64);
  int lane = threadIdx.x & 63, w = threadIdx.x >> 6;
  if (lane == 0) ws[w] = v;
  __syncthreads();
  if (threadIdx.x == 0) {
    float t = 0.f;
    #pragma unroll
    for (int i = 0; i < 8; ++i) t += ws[i];
    tot = t;
  }
  __syncthreads();
  return tot;
}

// ---------------- W (f32, [k][n]) -> Wt (fp16, [n][k]) ----------------
__global__ __launch_bounds__(256) void transpose_w(
    const float* __restrict__ W, unsigned short* __restrict__ Wt) {
  __shared__ float tile[64][65];
  int n0 = blockIdx.x * 64;
  int k0 = blockIdx.y * 64;
  int t = threadIdx.x;
  int r = t >> 4, c4 = (t & 15) * 4;
  #pragma unroll
  for (int p = 0; p < 4; ++p) {
    f32x4 v = *(const f32x4*)(W + (size_t)(k0 + r + 16 * p) * NDIM + n0 + c4);
    tile[r + 16 * p][c4 + 0] = v[0];
    tile[r + 16 * p][c4 + 1] = v[1];
    tile[r + 16 * p][c4 + 2] = v[2];
    tile[r + 16 * p][c4 + 3] = v[3];
  }
  __syncthreads();
  #pragma unroll
  for (int p = 0; p < 4; ++p) {
    int nr = r + 16 * p;
    u16x4 o;
    #pragma unroll
    for (int j = 0; j < 4; ++j) o[j] = f2h(tile[c4 + j][nr]);
    *(u16x4*)(Wt + (size_t)(n0 + nr) * NDIM + k0 + c4) = o;
  }
}

// ---------------- column multipliers from scatter positions ----------------
__global__ void init_colmul(const float* __restrict__ iscale,
                            const float* __restrict__ oscale,
                            const int* __restrict__ ipos, const int* __restrict__ opos,
                            float* __restrict__ icm, float* __restrict__ ocm) {
  int c = blockIdx.x * 256 + threadIdx.x;
  if (c >= NDIM) return;
  float iv = 1.f, ov = 1.f;
  #pragma unroll
  for (int i = 0; i < 16; ++i) {
    if (ipos[i] == c) iv *= iscale[i];
    if (opos[i] == c) ov *= oscale[i];
  }
  icm[c] = iv; ocm[c] = ov;
}

// ---------------- step 0: h1 = norm(tanh(B + x*icm)) ----------------
__global__ __launch_bounds__(512) void step0_kernel(
    const float* __restrict__ x, const float* __restrict__ bias,
    const float* __restrict__ icm, const float* __restrict__ nw,
    const float* __restrict__ ocm,
    unsigned short* __restrict__ hbuf, float* __restrict__ out) {
  int row = blockIdx.x;
  int tid = threadIdx.x;
  const float* xr = x + (size_t)row * NDIM;
  float a[8];
  float sq = 0.f;
  #pragma unroll
  for (int p = 0; p < 2; ++p) {
    int c = p * 2048 + tid * 4;
    f32x4 xv = *(const f32x4*)(xr + c);
    f32x4 bv = *(const f32x4*)(bias + c);
    f32x4 ic = *(const f32x4*)(icm + c);
    #pragma unroll
    for (int j = 0; j < 4; ++j) {
      float av = tanhf(bv[j] + xv[j] * ic[j]);
      a[p * 4 + j] = av;
      sq += av * av;
    }
  }
  float tot = block_reduce_sum_512(sq);
  float scale = rsqrtf(tot * (1.0f / NDIM) + EPS_RMS);
  unsigned short* hrow = hbuf + (size_t)row * NDIM;
  float* orow = out + (size_t)row * STEPS * NDIM;  // t = 0
  #pragma unroll
  for (int p = 0; p < 2; ++p) {
    int c = p * 2048 + tid * 4;
    f32x4 nv = *(const f32x4*)(nw + c);
    f32x4 oc = *(const f32x4*)(ocm + c);
    u16x4 hs; f32x4 os;
    #pragma unroll
    for (int j = 0; j < 4; ++j) {
      float h = a[p * 4 + j] * scale * nv[j];
      hs[j] = f2h(h);
      os[j] = h * oc[j];
    }
    *(u16x4*)(hrow + c) = hs;
    *(f32x4*)(orow + c) = os;
  }
}

// ---------------- GEMM: pbuf[ks] = (h @ W)[128x128 tile, K-slice] ----------------
// grid (32, 2, ksplit) -> 512 blocks at ksplit=8 (2 blocks/CU, 8 waves/CU).
// 4 waves as 2x2, wave-tile 64x64 (4x4 of 16x16x32) = 32 FLOP per LDS byte.
// global_load_lds(16B) staging, involution chunk-swizzle, LDS dbuf, counted vmcnt.
__global__ __launch_bounds__(256, 2) void gemm_kernel(
    const unsigned short* __restrict__ A,   // h fp16 [256][4096]
    const unsigned short* __restrict__ Bt,  // Wt fp16 [n][k]
    float* __restrict__ pbuf,               // [ksplit][256][4096] f32
    int kslen) {
  __shared__ __align__(16) unsigned short As[2][128 * 64];
  __shared__ __align__(16) unsigned short Bs[2][128 * 64];
  const int tid = threadIdx.x;
  const int n0 = blockIdx.x * 128;
  const int m0 = blockIdx.y * 128;
  const int ks = blockIdx.z;
  const int kbase = ks * kslen;
  const int nit = kslen >> 6;            // BK=64 iterations
  const int wave = tid >> 6, lane = tid & 63;
  const int wm = (wave >> 1) * 64, wn = (wave & 1) * 64;
  const int l15 = lane & 15;
  const int g = lane >> 4;               // 0..3 k-group
  const int q = l15 & 7;                 // read-side swizzle key (row&7)
  const int srow = tid >> 3;             // 0..31 staging row-in-group
  const int sch = tid & 7;               // staging chunk
  const int koff = (sch ^ (srow & 7)) * 8;  // involution-swizzled k offset

  const unsigned short* aP[4];
  const unsigned short* bP[4];
  #pragma unroll
  for (int i = 0; i < 4; ++i) {
    aP[i] = A + (size_t)(m0 + i * 32 + srow) * NDIM + kbase + koff;
    bP[i] = Bt + (size_t)(n0 + i * 32 + srow) * NDIM + kbase + koff;
  }

  f32x4 acc[4][4];
  f32x4 zero = {0.f, 0.f, 0.f, 0.f};
  #pragma unroll
  for (int i = 0; i < 4; ++i)
    #pragma unroll
    for (int j = 0; j < 4; ++j) acc[i][j] = zero;

  // prologue: stage k-tile 0 into buffer 0
  #pragma unroll
  for (int i = 0; i < 4; ++i)
    GLDS16(aP[i], &As[0][(i * 32 + srow) * 64 + sch * 8]);
  #pragma unroll
  for (int i = 0; i < 4; ++i)
    GLDS16(bP[i], &Bs[0][(i * 32 + srow) * 64 + sch * 8]);

  for (int it = 0; it < nit; ++it) {
    const int p = it & 1;
    SBAR();   // all waves done reading buf[1-p]
    if (it < nit - 1) {
      const int kb = (it + 1) * 64;
      #pragma unroll
      for (int i = 0; i < 4; ++i)
        GLDS16(aP[i] + kb, &As[1 - p][(i * 32 + srow) * 64 + sch * 8]);
      #pragma unroll
      for (int i = 0; i < 4; ++i)
        GLDS16(bP[i] + kb, &Bs[1 - p][(i * 32 + srow) * 64 + sch * 8]);
      asm volatile("s_waitcnt vmcnt(8)" ::: "memory");  // tile `it` landed
    } else {
      asm volatile("s_waitcnt vmcnt(0)" ::: "memory");
    }
    SBAR();   // tile `it` visible to all waves
    #pragma unroll
    for (int kk = 0; kk < 2; ++kk) {
      f16x8 af[4], bfr[4];
      #pragma unroll
      for (int mf = 0; mf < 4; ++mf) {
        int row = wm + mf * 16 + l15;
        af[mf] = *(const f16x8*)&As[p][row * 64 + (((kk << 2) + g) ^ q) * 8];
      }
      #pragma unroll
      for (int nf = 0; nf < 4; ++nf) {
        int row = wn + nf * 16 + l15;
        bfr[nf] = *(const f16x8*)&Bs[p][row * 64 + (((kk << 2) + g) ^ q) * 8];
      }
      #pragma unroll
      for (int mf = 0; mf < 4; ++mf)
        #pragma unroll
        for (int nf = 0; nf < 4; ++nf)
          acc[mf][nf] = __builtin_amdgcn_mfma_f32_16x16x32_f16(af[mf], bfr[nf], acc[mf][nf], 0, 0, 0);
    }
  }

  float* pout = pbuf + (size_t)ks * BATCH * NDIM;
  const int crow = g * 4;
  #pragma unroll
  for (int mf = 0; mf < 4; ++mf) {
    #pragma unroll
    for (int nf = 0; nf < 4; ++nf) {
      int col = n0 + wn + nf * 16 + l15;
      #pragma unroll
      for (int r = 0; r < 4; ++r) {
        int row = m0 + wm + mf * 16 + crow + r;
        pout[(size_t)row * NDIM + col] = acc[mf][nf][r];
      }
    }
  }
}

// ---------------- combine splits + bias + tanh + RMSNorm + outputs ----------------
__global__ __launch_bounds__(512) void normalize_kernel(
    const float* __restrict__ pbuf, const float* __restrict__ bias,
    const float* __restrict__ nw, const float* __restrict__ ocm,
    unsigned short* __restrict__ hbuf, float* __restrict__ out,
    float* __restrict__ hfin, int t, int is_last, int ksplit) {
  const size_t SL = (size_t)BATCH * NDIM;
  int row = blockIdx.x;
  int tid = threadIdx.x;
  const float* p0 = pbuf + (size_t)row * NDIM;
  float a[8];
  float sq = 0.f;
  #pragma unroll
  for (int p = 0; p < 2; ++p) {
    int c = p * 2048 + tid * 4;
    f32x4 s = *(const f32x4*)(p0 + c);
    for (int k = 1; k < ksplit; ++k)
      s += *(const f32x4*)(p0 + (size_t)k * SL + c);
    f32x4 bv = *(const f32x4*)(bias + c);
    #pragma unroll
    for (int j = 0; j < 4; ++j) {
      float av = tanhf(s[j] + bv[j]);
      a[p * 4 + j] = av;
      sq += av * av;
    }
  }
  float tot = block_reduce_sum_512(sq);
  float scale = rsqrtf(tot * (1.0f / NDIM) + EPS_RMS);
  unsigned short* hrow = hbuf + (size_t)row * NDIM;
  float* orow = out + ((size_t)row * STEPS + t) * NDIM;
  #pragma unroll
  for (int p = 0; p < 2; ++p) {
    int c = p * 2048 + tid * 4;
    f32x4 nv = *(const f32x4*)(nw + c);
    f32x4 oc = *(const f32x4*)(ocm + c);
    u16x4 hs; f32x4 os; f32x4 hv;
    #pragma unroll
    for (int j = 0; j < 4; ++j) {
      float h = a[p * 4 + j] * scale * nv[j];
      hv[j] = h;
      hs[j] = f2h(h);
      os[j] = h * oc[j];
    }
    *(u16x4*)(hrow + c) = hs;
    *(f32x4*)(orow + c) = os;
    if (is_last) *(f32x4*)(hfin + (size_t)row * NDIM + c) = hv;
  }
}

extern "C" void kernel_launch(void* const* d_in, const int* in_sizes, int n_in,
                              void* d_out, int out_size, void* d_ws, size_t ws_size,
                              hipStream_t stream) {
  (void)in_sizes; (void)n_in; (void)out_size;
  const float* x      = (const float*)d_in[0];
  const float* W      = (const float*)d_in[1];
  const float* Bb     = (const float*)d_in[2];
  const float* iscale = (const float*)d_in[3];
  const float* oscale = (const float*)d_in[4];
  const float* nw     = (const float*)d_in[5];
  const int* ipos = (const int*)d_in[6];
  const int* opos = (const int*)d_in[7];
  // d_in[8] = steps (fixed at 16 by the problem spec).

  char* ws = (char*)d_ws;
  unsigned short* Wt   = (unsigned short*)(ws);             // 32 MiB fp16
  unsigned short* hbuf = (unsigned short*)(ws + 33554432);  // 2 MiB fp16
  float* icm           = (float*)(ws + 35651584);           // 16 KiB
  float* ocm           = (float*)(ws + 35667968);           // 16 KiB
  float* pbuf          = (float*)(ws + 35684352);           // up to 32 MiB

  // splitK=8 needs ~66 MiB total; fall back to 4 if the workspace is tight.
  size_t need8 = 35684352 + (size_t)8 * BATCH * NDIM * sizeof(float);
  int ksplit = (ws_size >= need8) ? 8 : 4;
  int kslen = NDIM / ksplit;

  float* out  = (float*)d_out;
  float* hfin = out + (size_t)BATCH * STEPS * NDIM;

  hipLaunchKernelGGL(transpose_w, dim3(64, 64), dim3(256), 0, stream, W, Wt);
  hipLaunchKernelGGL(init_colmul, dim3(16), dim3(256), 0, stream,
                     iscale, oscale, ipos, opos, icm, ocm);
  hipLaunchKernelGGL(step0_kernel, dim3(256), dim3(512), 0, stream,
                     x, Bb, icm, nw, ocm, hbuf, out);
  for (int t = 1; t < STEPS; ++t) {
    hipLaunchKernelGGL(gemm_kernel, dim3(32, 2, ksplit), dim3(256), 0, stream,
                       hbuf, Wt, pbuf, kslen);
    hipLaunchKernelGGL(normalize_kernel, dim3(256), dim3(512), 0, stream,
                       pbuf, Bb, nw, ocm, hbuf, out, hfin, t,
                       (t == STEPS - 1) ? 1 : 0, ksplit);
  }
}